// Round 3
// baseline (37.529 us; speedup 1.0000x reference)
//
#include <hip/hip_runtime.h>

#define B 8
#define S 2048
#define NBLK_PER_SAMPLE 128
#define NBLK_INTER (B * NBLK_PER_SAMPLE)   // 1024
#define NBLK_LOSS 64
#define NBLK_TOTAL (NBLK_INTER + NBLK_LOSS) // 1088
#define TPB2 256

// ---------------------------------------------------------------------------
// Workspace layout (everything rewritten every launch -> re-poison safe):
//   [0,4)        int   done_cnt          (zeroed by kernel A each launch)
//   [64,96)      int   n_buf[8]
//   [128,4224)   float partial[1024]     intersection per-block sums
//   [4224,5504)  float acc2[64][5]       loss per-block sums
//   [8192,+128K) float2 pts_c[8][2048]   compacted points
// ---------------------------------------------------------------------------

// ---------------------------------------------------------------------------
// Kernel A: stable compaction of point_pred by non_none. 8 blocks x 1024.
// Also zero-initializes the done counter for kernel B.
// ---------------------------------------------------------------------------
__global__ __launch_bounds__(1024) void compact_kernel(
    const float4* __restrict__ point_pred,   // viewed as float4 = 2 points
    const float*  __restrict__ target_seq,
    const int2*   __restrict__ padding_mask, // viewed as int2
    int*   __restrict__ done_cnt,
    int*   __restrict__ n_buf,
    float2* __restrict__ pts_c)
{
    const int b = blockIdx.x;
    const int tid = threadIdx.x;
    const int base = b * S;

    if (b == 0 && tid == 0) *done_cnt = 0;

    const int2 mk = padding_mask[(base >> 1) + tid];
    const float t4a = target_seq[(base + tid * 2 + 0) * 5 + 4];
    const float t4b = target_seq[(base + tid * 2 + 1) * 5 + 4];
    const float4 pp = point_pred[(base >> 1) + tid];
    const int f0 = (mk.x == 0 && (int)t4a != 0) ? 1 : 0;
    const int f1 = (mk.y == 0 && (int)t4b != 0) ? 1 : 0;

    // ---- block-wide scan over flags (stable compaction) ----
    const int lane = tid & 63;
    const int wv = tid >> 6;
    const int tsum = f0 + f1;
    int inc = tsum;
    #pragma unroll
    for (int off = 1; off < 64; off <<= 1) {
        int u = __shfl_up(inc, (unsigned)off, 64);
        if (lane >= off) inc += u;
    }
    __shared__ int wsum[16], woff[16];
    if (lane == 63) wsum[wv] = inc;
    __syncthreads();
    if (tid == 0) {
        int run = 0;
        #pragma unroll
        for (int w = 0; w < 16; ++w) { woff[w] = run; run += wsum[w]; }
        n_buf[b] = run;
    }
    __syncthreads();
    const int pos = base + woff[wv] + (inc - tsum);
    if (f0) pts_c[pos] = make_float2(pp.x, pp.y);
    if (f1) pts_c[pos + f0] = make_float2(pp.z, pp.w);
}

// ---------------------------------------------------------------------------
// Kernel B: role-split mega-kernel.
//   blocks [0,1024):    soft segment-intersection partial sums
//   blocks [1024,1088): per-element cls/pt/orient loss partial sums
//   last block to finish: final reduction + output write
// ---------------------------------------------------------------------------
__global__ __launch_bounds__(TPB2) void fused_kernel(
    const float2* __restrict__ point_pred,
    const float2* __restrict__ orient_pred,
    const float4* __restrict__ class_pred,
    const float*  __restrict__ target_seq,
    const int*    __restrict__ padding_mask,
    const float2* __restrict__ pts_c,
    const int*    __restrict__ n_buf,
    int*   __restrict__ done_cnt,
    float* __restrict__ partial,   // [1024]
    float* __restrict__ acc2,      // [64][5]
    float* __restrict__ out)
{
    __shared__ float2 sp[S];                  // 16 KB
    __shared__ float red[TPB2 / 64][5];
    __shared__ int last_flag;

    const int blk = blockIdx.x;
    const int tid = threadIdx.x;
    const int lane = tid & 63, wv = tid >> 6;

    if (blk < NBLK_INTER) {
        // ---------------- intersection role ----------------
        const int b = blk / NBLK_PER_SAMPLE;
        const int iblk = blk % NBLK_PER_SAMPLE;
        const int n = n_buf[b];
        float local = 0.f;
        if (n >= 4) {                         // uniform across block
            const int n_seg = n - 1;
            const float2* pb = pts_c + b * S;
            for (int k = tid; k < n; k += TPB2) sp[k] = pb[k];
            __syncthreads();
            for (int i = iblk; i < n_seg - 2; i += NBLK_PER_SAMPLE) {
                const float2 q1 = sp[i];
                const float2 q2 = sp[i + 1];
                const float e12x = q2.x - q1.x, e12y = q2.y - q1.y;
                const int jmax = (i == 0) ? n_seg - 1 : n_seg;  // wrap-pair excl.
                for (int j = i + 2 + tid; j < jmax; j += TPB2) {
                    const float2 q3 = sp[j];
                    const float2 q4 = sp[j + 1];
                    const float e34x = q4.x - q3.x, e34y = q4.y - q3.y;
                    const float ce = e12x * e34y - e12y * e34x;
                    const float rx = q1.x - q3.x, ry = q1.y - q3.y;
                    const float d1 = e34x * ry - e34y * rx;
                    const float d3 = e12y * rx - e12x * ry;
                    const float d2 = d1 - ce;
                    const float d4 = d3 + ce;
                    const float ea = __expf(d1 * d2 * 0.01f);
                    const float eb = __expf(d3 * d4 * 0.01f);
                    local += __builtin_amdgcn_rcpf((1.f + ea) * (1.f + eb));
                }
            }
        }
        #pragma unroll
        for (int off = 32; off > 0; off >>= 1)
            local += __shfl_down(local, (unsigned)off, 64);
        if (lane == 0) red[wv][0] = local;
        __syncthreads();
        if (tid == 0)
            partial[blk] = red[0][0] + red[1][0] + red[2][0] + red[3][0];
    } else {
        // ---------------- per-element loss role ----------------
        const int idx = (blk - NBLK_INTER) * TPB2 + tid;   // [0, B*S)
        const bool valid = (padding_mask[idx] == 0);
        const float t4 = target_seq[idx * 5 + 4];
        const int tc = (int)t4;
        const bool nn = valid && (tc != 0);
        float cls_acc = 0.f, pt_acc = 0.f, or_acc = 0.f, v_acc = 0.f, nn_acc = 0.f;
        if (valid) {
            const float4 c = class_pred[idx];
            const float m = fmaxf(fmaxf(c.x, c.y), fmaxf(c.z, c.w));
            const float lse = m + logf(expf(c.x - m) + expf(c.y - m) +
                                       expf(c.z - m) + expf(c.w - m));
            const float ct = (tc == 0) ? c.x : (tc == 1) ? c.y : (tc == 2) ? c.z : c.w;
            cls_acc = lse - ct;
            v_acc = 1.f;
        }
        if (nn) {
            const float2 pp = point_pred[idx];
            const float tx = target_seq[idx * 5 + 0];
            const float ty = target_seq[idx * 5 + 1];
            const float dx = (pp.x - tx) * (1.0f / 224.0f);
            const float dy = (pp.y - ty) * (1.0f / 224.0f);
            const float adx = fabsf(dx), ady = fabsf(dy);
            const float l0 = (adx < 1.f) ? 0.5f * dx * dx : adx - 0.5f;
            const float l1 = (ady < 1.f) ? 0.5f * dy * dy : ady - 0.5f;
            pt_acc = 0.5f * (l0 + l1);
            const float2 op = orient_pred[idx];
            const float ox = target_seq[idx * 5 + 2];
            const float oy = target_seq[idx * 5 + 3];
            or_acc = 1.f - (op.x * ox + op.y * oy);
            nn_acc = 1.f;
        }
        #pragma unroll
        for (int off = 32; off > 0; off >>= 1) {
            cls_acc += __shfl_down(cls_acc, (unsigned)off, 64);
            pt_acc  += __shfl_down(pt_acc,  (unsigned)off, 64);
            or_acc  += __shfl_down(or_acc,  (unsigned)off, 64);
            v_acc   += __shfl_down(v_acc,   (unsigned)off, 64);
            nn_acc  += __shfl_down(nn_acc,  (unsigned)off, 64);
        }
        if (lane == 0) {
            red[wv][0] = cls_acc; red[wv][1] = pt_acc; red[wv][2] = or_acc;
            red[wv][3] = v_acc;   red[wv][4] = nn_acc;
        }
        __syncthreads();
        if (tid == 0) {
            float* dst = acc2 + (blk - NBLK_INTER) * 5;
            #pragma unroll
            for (int c5 = 0; c5 < 5; ++c5)
                dst[c5] = red[0][c5] + red[1][c5] + red[2][c5] + red[3][c5];
        }
    }

    // ---------------- arrive; last block finalizes ----------------
    if (tid == 0) {
        __threadfence();
        const int old = atomicAdd(done_cnt, 1);
        last_flag = (old == NBLK_TOTAL - 1) ? 1 : 0;
    }
    __syncthreads();
    if (!last_flag) return;
    __threadfence();

    // intersection sum: 1024 partials
    float s = partial[tid] + partial[tid + 256] + partial[tid + 512] + partial[tid + 768];
    #pragma unroll
    for (int off = 32; off > 0; off >>= 1)
        s += __shfl_down(s, (unsigned)off, 64);
    if (lane == 0) red[wv][0] = s;
    __syncthreads();
    const float inter_sum = red[0][0] + red[1][0] + red[2][0] + red[3][0];
    __syncthreads();

    // loss sums: 64 x 5
    float a0 = 0, a1 = 0, a2 = 0, a3 = 0, a4 = 0;
    if (tid < NBLK_LOSS) {
        a0 = acc2[tid * 5 + 0]; a1 = acc2[tid * 5 + 1]; a2 = acc2[tid * 5 + 2];
        a3 = acc2[tid * 5 + 3]; a4 = acc2[tid * 5 + 4];
    }
    #pragma unroll
    for (int off = 32; off > 0; off >>= 1) {
        a0 += __shfl_down(a0, (unsigned)off, 64);
        a1 += __shfl_down(a1, (unsigned)off, 64);
        a2 += __shfl_down(a2, (unsigned)off, 64);
        a3 += __shfl_down(a3, (unsigned)off, 64);
        a4 += __shfl_down(a4, (unsigned)off, 64);
    }
    if (lane == 0) {
        red[wv][0] = a0; red[wv][1] = a1; red[wv][2] = a2;
        red[wv][3] = a3; red[wv][4] = a4;
    }
    __syncthreads();
    if (tid == 0) {
        const float cls_sum = red[0][0] + red[1][0];
        const float pt_sum  = red[0][1] + red[1][1];
        const float or_sum  = red[0][2] + red[1][2];
        const float vcnt    = red[0][3] + red[1][3];
        const float nncnt   = red[0][4] + red[1][4];
        long long cnt = 0;
        #pragma unroll
        for (int b2 = 0; b2 < B; ++b2) {
            const int n = n_buf[b2];
            if (n >= 4) {
                const long long ns = n - 1;
                cnt += (ns - 1) * (ns - 2) / 2 - 1;
            }
        }
        const float cls_loss = cls_sum / fmaxf(vcnt, 1.f);
        const float pt_loss = pt_sum / fmaxf(nncnt, 1.f);
        const float orient_loss = or_sum / fmaxf(nncnt, 1.f);
        const float intersect_loss = (cnt > 0) ? inter_sum / (float)cnt : 0.f;
        out[0] = 1.0f * pt_loss + 0.5f * orient_loss +
                 1.0f * cls_loss + 0.1f * intersect_loss;
        out[1] = pt_loss;
        out[2] = orient_loss;
        out[3] = cls_loss;
        out[4] = intersect_loss;
    }
}

extern "C" void kernel_launch(void* const* d_in, const int* in_sizes, int n_in,
                              void* d_out, int out_size, void* d_ws, size_t ws_size,
                              hipStream_t stream) {
    (void)in_sizes; (void)n_in; (void)out_size; (void)ws_size;
    const float2* point_pred  = (const float2*)d_in[0];
    const float2* orient_pred = (const float2*)d_in[1];
    const float4* class_pred  = (const float4*)d_in[2];
    const float*  target_seq  = (const float*)d_in[3];
    const int*    padding_mask = (const int*)d_in[4];

    int*    done_cnt = (int*)d_ws;
    int*    n_buf    = (int*)((char*)d_ws + 64);
    float*  partial  = (float*)((char*)d_ws + 128);
    float*  acc2     = (float*)((char*)d_ws + 4224);
    float2* pts_c    = (float2*)((char*)d_ws + 8192);

    compact_kernel<<<B, 1024, 0, stream>>>((const float4*)point_pred, target_seq,
                                           (const int2*)padding_mask,
                                           done_cnt, n_buf, pts_c);
    fused_kernel<<<NBLK_TOTAL, TPB2, 0, stream>>>(point_pred, orient_pred,
                                                  class_pred, target_seq,
                                                  padding_mask, pts_c, n_buf,
                                                  done_cnt, partial, acc2,
                                                  (float*)d_out);
}

// Round 4
// 20.131 us; speedup vs baseline: 1.8642x; 1.8642x over previous
//
#include <hip/hip_runtime.h>

#define B 8
#define S 2048
#define NBPS 128                       // inter blocks per sample
#define NBLK_INTER (B * NBPS)          // 1024
#define NBLK_LOSS 64
#define NBLK_TOTAL (NBLK_INTER + NBLK_LOSS)   // 1088
#define TPB 256

// ---------------------------------------------------------------------------
// Workspace layout (every slot rewritten every launch -> re-poison safe,
// no zeroing, no atomics anywhere):
//   [0,32)       int   n_buf[8]
//   [64,4160)    float partial[1024]   intersection per-block sums
//   [4224,5504)  float acc2[64][5]     loss per-block sums
// ---------------------------------------------------------------------------

// ---------------------------------------------------------------------------
// MEGA kernel: role-split, no cross-block dependencies.
//   blocks [0,1024):  per-sample IN-BLOCK compaction (redundant per block,
//                     but latency-free since all blocks are co-resident)
//                     followed by soft-intersection partial sums.
//   blocks [1024,1088): per-element cls/pt/orient losses (1 elem/thread).
// ---------------------------------------------------------------------------
__global__ __launch_bounds__(TPB) void mega_kernel(
    const float2* __restrict__ point_pred,
    const float2* __restrict__ orient_pred,
    const float4* __restrict__ class_pred,
    const float*  __restrict__ target_seq,
    const int*    __restrict__ padding_mask,
    int*   __restrict__ n_buf,
    float* __restrict__ partial,
    float* __restrict__ acc2)
{
    __shared__ float2 sp[S];                 // 16 KB
    __shared__ float red[TPB / 64][5];
    __shared__ int wsum[TPB / 64], woff[TPB / 64], nTot;

    const int blk = blockIdx.x;
    const int tid = threadIdx.x;
    const int lane = tid & 63, wv = tid >> 6;

    if (blk < NBLK_INTER) {
        // ================= intersection role =================
        const int b = blk >> 7;              // blk / NBPS
        const int iblk = blk & (NBPS - 1);
        const int base = b * S;
        const int e0 = tid * 8;              // 8 contiguous elems per thread

        // ---- loads (coalesced 32B/64B per thread for mask/points) ----
        const int4* pm4 = (const int4*)(padding_mask + base + e0);
        const int4 ma = pm4[0], mb = pm4[1];
        float t4v[8];
        #pragma unroll
        for (int k = 0; k < 8; ++k)
            t4v[k] = target_seq[(base + e0 + k) * 5 + 4];
        const float4* pq4 = (const float4*)(point_pred + base + e0);
        const float4 pa = pq4[0], pb = pq4[1], pc = pq4[2], pd = pq4[3];
        float2 p[8];
        p[0] = make_float2(pa.x, pa.y); p[1] = make_float2(pa.z, pa.w);
        p[2] = make_float2(pb.x, pb.y); p[3] = make_float2(pb.z, pb.w);
        p[4] = make_float2(pc.x, pc.y); p[5] = make_float2(pc.z, pc.w);
        p[6] = make_float2(pd.x, pd.y); p[7] = make_float2(pd.z, pd.w);
        int f[8];
        f[0] = (ma.x == 0 && (int)t4v[0] != 0) ? 1 : 0;
        f[1] = (ma.y == 0 && (int)t4v[1] != 0) ? 1 : 0;
        f[2] = (ma.z == 0 && (int)t4v[2] != 0) ? 1 : 0;
        f[3] = (ma.w == 0 && (int)t4v[3] != 0) ? 1 : 0;
        f[4] = (mb.x == 0 && (int)t4v[4] != 0) ? 1 : 0;
        f[5] = (mb.y == 0 && (int)t4v[5] != 0) ? 1 : 0;
        f[6] = (mb.z == 0 && (int)t4v[6] != 0) ? 1 : 0;
        f[7] = (mb.w == 0 && (int)t4v[7] != 0) ? 1 : 0;

        // ---- block scan over per-thread counts (stable compaction) ----
        const int c = f[0]+f[1]+f[2]+f[3]+f[4]+f[5]+f[6]+f[7];
        int inc = c;
        #pragma unroll
        for (int off = 1; off < 64; off <<= 1) {
            int u = __shfl_up(inc, (unsigned)off, 64);
            if (lane >= off) inc += u;
        }
        if (lane == 63) wsum[wv] = inc;
        __syncthreads();
        if (tid == 0) {
            int run = 0;
            #pragma unroll
            for (int w = 0; w < TPB / 64; ++w) { woff[w] = run; run += wsum[w]; }
            nTot = run;
        }
        __syncthreads();
        int pos = woff[wv] + inc - c;        // exclusive prefix
        #pragma unroll
        for (int k = 0; k < 8; ++k) { if (f[k]) sp[pos++] = p[k]; }
        __syncthreads();

        const int n = nTot;
        if (iblk == 0 && tid == 0) n_buf[b] = n;

        // ---- pair loop ----
        float local = 0.f;
        if (n >= 4) {
            const int n_seg = n - 1;
            for (int i = iblk; i < n_seg - 2; i += NBPS) {
                const float2 q1 = sp[i], q2 = sp[i + 1];
                const float e12x = q2.x - q1.x, e12y = q2.y - q1.y;
                const int jmax = (i == 0) ? n_seg - 1 : n_seg;  // wrap-pair excl.
                for (int j = i + 2 + tid; j < jmax; j += TPB) {
                    const float2 q3 = sp[j], q4 = sp[j + 1];
                    const float e34x = q4.x - q3.x, e34y = q4.y - q3.y;
                    const float ce = e12x * e34y - e12y * e34x;
                    const float rx = q1.x - q3.x, ry = q1.y - q3.y;
                    const float d1 = e34x * ry - e34y * rx;
                    const float d3 = e12y * rx - e12x * ry;
                    const float d2 = d1 - ce;
                    const float d4 = d3 + ce;
                    const float ea = __expf(d1 * d2 * 0.01f);
                    const float eb = __expf(d3 * d4 * 0.01f);
                    // sigmoid(z1)*sigmoid(z2) = 1/((1+ea)(1+eb)); inf->rcp->0 ok
                    local += __builtin_amdgcn_rcpf((1.f + ea) * (1.f + eb));
                }
            }
        }
        #pragma unroll
        for (int off = 32; off > 0; off >>= 1)
            local += __shfl_down(local, (unsigned)off, 64);
        if (lane == 0) red[wv][0] = local;
        __syncthreads();
        if (tid == 0)
            partial[blk] = red[0][0] + red[1][0] + red[2][0] + red[3][0];
    } else {
        // ================= per-element loss role =================
        const int idx = (blk - NBLK_INTER) * TPB + tid;   // [0, B*S)
        const bool valid = (padding_mask[idx] == 0);
        const float t4 = target_seq[idx * 5 + 4];
        const int tc = (int)t4;
        const bool nn = valid && (tc != 0);
        float cls_acc = 0.f, pt_acc = 0.f, or_acc = 0.f, v_acc = 0.f, nn_acc = 0.f;
        if (valid) {
            const float4 cl = class_pred[idx];
            const float m = fmaxf(fmaxf(cl.x, cl.y), fmaxf(cl.z, cl.w));
            const float lse = m + logf(expf(cl.x - m) + expf(cl.y - m) +
                                       expf(cl.z - m) + expf(cl.w - m));
            const float ct = (tc == 0) ? cl.x : (tc == 1) ? cl.y : (tc == 2) ? cl.z : cl.w;
            cls_acc = lse - ct;
            v_acc = 1.f;
        }
        if (nn) {
            const float2 pp = point_pred[idx];
            const float tx = target_seq[idx * 5 + 0];
            const float ty = target_seq[idx * 5 + 1];
            const float dx = (pp.x - tx) * (1.0f / 224.0f);
            const float dy = (pp.y - ty) * (1.0f / 224.0f);
            const float adx = fabsf(dx), ady = fabsf(dy);
            const float l0 = (adx < 1.f) ? 0.5f * dx * dx : adx - 0.5f;
            const float l1 = (ady < 1.f) ? 0.5f * dy * dy : ady - 0.5f;
            pt_acc = 0.5f * (l0 + l1);
            const float2 op = orient_pred[idx];
            const float ox = target_seq[idx * 5 + 2];
            const float oy = target_seq[idx * 5 + 3];
            or_acc = 1.f - (op.x * ox + op.y * oy);
            nn_acc = 1.f;
        }
        #pragma unroll
        for (int off = 32; off > 0; off >>= 1) {
            cls_acc += __shfl_down(cls_acc, (unsigned)off, 64);
            pt_acc  += __shfl_down(pt_acc,  (unsigned)off, 64);
            or_acc  += __shfl_down(or_acc,  (unsigned)off, 64);
            v_acc   += __shfl_down(v_acc,   (unsigned)off, 64);
            nn_acc  += __shfl_down(nn_acc,  (unsigned)off, 64);
        }
        if (lane == 0) {
            red[wv][0] = cls_acc; red[wv][1] = pt_acc; red[wv][2] = or_acc;
            red[wv][3] = v_acc;   red[wv][4] = nn_acc;
        }
        __syncthreads();
        if (tid == 0) {
            float* dst = acc2 + (blk - NBLK_INTER) * 5;
            #pragma unroll
            for (int c5 = 0; c5 < 5; ++c5)
                dst[c5] = red[0][c5] + red[1][c5] + red[2][c5] + red[3][c5];
        }
    }
}

// ---------------------------------------------------------------------------
// Finalize: 1 block. Kernel boundary provides cross-XCD visibility.
// ---------------------------------------------------------------------------
__global__ __launch_bounds__(TPB) void finalize_kernel(
    const float* __restrict__ acc2,
    const int* __restrict__ n_buf,
    const float* __restrict__ partial,
    float* __restrict__ out)
{
    __shared__ float red[TPB / 64][5];
    const int tid = threadIdx.x;
    const int lane = tid & 63, wv = tid >> 6;

    float s = partial[tid] + partial[tid + 256] + partial[tid + 512] + partial[tid + 768];
    #pragma unroll
    for (int off = 32; off > 0; off >>= 1)
        s += __shfl_down(s, (unsigned)off, 64);
    if (lane == 0) red[wv][0] = s;
    __syncthreads();
    const float inter_sum = red[0][0] + red[1][0] + red[2][0] + red[3][0];
    __syncthreads();

    float a0 = 0, a1 = 0, a2 = 0, a3 = 0, a4 = 0;
    if (tid < NBLK_LOSS) {
        a0 = acc2[tid * 5 + 0]; a1 = acc2[tid * 5 + 1]; a2 = acc2[tid * 5 + 2];
        a3 = acc2[tid * 5 + 3]; a4 = acc2[tid * 5 + 4];
    }
    #pragma unroll
    for (int off = 32; off > 0; off >>= 1) {
        a0 += __shfl_down(a0, (unsigned)off, 64);
        a1 += __shfl_down(a1, (unsigned)off, 64);
        a2 += __shfl_down(a2, (unsigned)off, 64);
        a3 += __shfl_down(a3, (unsigned)off, 64);
        a4 += __shfl_down(a4, (unsigned)off, 64);
    }
    if (lane == 0) {
        red[wv][0] = a0; red[wv][1] = a1; red[wv][2] = a2;
        red[wv][3] = a3; red[wv][4] = a4;
    }
    __syncthreads();
    if (tid == 0) {
        const float cls_sum = red[0][0] + red[1][0] + red[2][0] + red[3][0];
        const float pt_sum  = red[0][1] + red[1][1] + red[2][1] + red[3][1];
        const float or_sum  = red[0][2] + red[1][2] + red[2][2] + red[3][2];
        const float vcnt    = red[0][3] + red[1][3] + red[2][3] + red[3][3];
        const float nncnt   = red[0][4] + red[1][4] + red[2][4] + red[3][4];
        long long cnt = 0;
        #pragma unroll
        for (int b2 = 0; b2 < B; ++b2) {
            const int n = n_buf[b2];
            if (n >= 4) {
                const long long ns = n - 1;
                cnt += (ns - 1) * (ns - 2) / 2 - 1;
            }
        }
        const float cls_loss = cls_sum / fmaxf(vcnt, 1.f);
        const float pt_loss = pt_sum / fmaxf(nncnt, 1.f);
        const float orient_loss = or_sum / fmaxf(nncnt, 1.f);
        const float intersect_loss = (cnt > 0) ? inter_sum / (float)cnt : 0.f;
        out[0] = 1.0f * pt_loss + 0.5f * orient_loss +
                 1.0f * cls_loss + 0.1f * intersect_loss;
        out[1] = pt_loss;
        out[2] = orient_loss;
        out[3] = cls_loss;
        out[4] = intersect_loss;
    }
}

extern "C" void kernel_launch(void* const* d_in, const int* in_sizes, int n_in,
                              void* d_out, int out_size, void* d_ws, size_t ws_size,
                              hipStream_t stream) {
    (void)in_sizes; (void)n_in; (void)out_size; (void)ws_size;
    const float2* point_pred  = (const float2*)d_in[0];
    const float2* orient_pred = (const float2*)d_in[1];
    const float4* class_pred  = (const float4*)d_in[2];
    const float*  target_seq  = (const float*)d_in[3];
    const int*    padding_mask = (const int*)d_in[4];

    int*   n_buf   = (int*)d_ws;
    float* partial = (float*)((char*)d_ws + 64);
    float* acc2    = (float*)((char*)d_ws + 4224);

    mega_kernel<<<NBLK_TOTAL, TPB, 0, stream>>>(point_pred, orient_pred,
                                                class_pred, target_seq,
                                                padding_mask,
                                                n_buf, partial, acc2);
    finalize_kernel<<<1, TPB, 0, stream>>>(acc2, n_buf, partial, (float*)d_out);
}